// Round 12
// baseline (217.753 us; speedup 1.0000x reference)
//
#include <hip/hip_runtime.h>
#include <math.h>

#define BB  2
#define TT  2048
#define SSQ 2048
#define DD  1024
#define HH  16
#define DKK 64
#define MM  (BB*TT)      // 4096 rows of activations
#define NN  (HH*DKK)     // 1024 proj width

typedef __attribute__((ext_vector_type(8))) short short8;
typedef __attribute__((ext_vector_type(4))) float f32x4;
typedef __attribute__((ext_vector_type(2))) unsigned int uint2v;
typedef __attribute__((ext_vector_type(4))) unsigned int u32x4;

__device__ __forceinline__ short f2bf(float x) {
    unsigned u = __builtin_bit_cast(unsigned, x);
    unsigned r = (u + 0x7FFFu + ((u >> 16) & 1u)) >> 16;
    return (short)r;
}

// pack two f32 into a bf16x2 word by truncation
__device__ __forceinline__ unsigned pk2(float lo, float hi) {
    return (__builtin_bit_cast(unsigned, hi) & 0xFFFF0000u) |
           (__builtin_bit_cast(unsigned, lo) >> 16);
}

// 8x f32 -> 8x bf16 via v_cvt_pk_bf16_f32 (RNE), 4 instrs
__device__ __forceinline__ short8 cvt8(f32x4 x, f32x4 y) {
    unsigned r0, r1, r2, r3;
    asm("v_cvt_pk_bf16_f32 %0, %1, %2" : "=v"(r0) : "v"(x[0]), "v"(x[1]));
    asm("v_cvt_pk_bf16_f32 %0, %1, %2" : "=v"(r1) : "v"(x[2]), "v"(x[3]));
    asm("v_cvt_pk_bf16_f32 %0, %1, %2" : "=v"(r2) : "v"(y[0]), "v"(y[1]));
    asm("v_cvt_pk_bf16_f32 %0, %1, %2" : "=v"(r3) : "v"(y[2]), "v"(y[3]));
    u32x4 r;
    r[0] = r0; r[1] = r1; r[2] = r2; r[3] = r3;
    return __builtin_bit_cast(short8, r);
}

__device__ __forceinline__ void glds16(const void* g, void* l) {
    __builtin_amdgcn_global_load_lds(
        (const __attribute__((address_space(1))) void*)g,
        (__attribute__((address_space(3))) void*)l, 16, 0, 0);
}

// ---------------------------------------------------------------------------
// wprep: weight transpose+convert fp32 [K][N] -> bf16 [N][K]. Grid 1024:
// z = id>>8 picks Wq/Wk/Wv/Wo. (Activation-convert pass deleted round 12 --
// gemm_qkv now stages fp32 A directly via glds16 + cvt-on-read.)
// ---------------------------------------------------------------------------
__global__ __launch_bounds__(256)
void wprep(const float* __restrict__ w0, const float* __restrict__ w1,
           const float* __restrict__ w2, const float* __restrict__ w3,
           short* __restrict__ t0, short* __restrict__ t1,
           short* __restrict__ t2, short* __restrict__ t3)
{
    __shared__ float Ls[64][65];
    const int id = blockIdx.x;
    const int tid = threadIdx.x;
    const int z = id >> 8;
    const int rem = id & 255;
    const float* in = (z == 0) ? w0 : (z == 1) ? w1 : (z == 2) ? w2 : w3;
    short* out = (z == 0) ? t0 : (z == 1) ? t1 : (z == 2) ? t2 : t3;
    const int c0 = (rem & 15) * 64, r0 = (rem >> 4) * 64;
    const int r = tid >> 2, c4 = tid & 3;

    const float* src = in + (size_t)(r0 + r) * DD + c0 + c4 * 16;
#pragma unroll
    for (int i = 0; i < 4; i++) {
        f32x4 f = *(const f32x4*)(src + i * 4);
#pragma unroll
        for (int j = 0; j < 4; j++) Ls[r][c4 * 16 + i * 4 + j] = f[j];
    }
    __syncthreads();

    short8 va, vb;
#pragma unroll
    for (int j = 0; j < 8; j++) va[j] = f2bf(Ls[c4 * 16 + j][r]);
#pragma unroll
    for (int j = 0; j < 8; j++) vb[j] = f2bf(Ls[c4 * 16 + 8 + j][r]);
    short* dst = out + (size_t)(c0 + r) * DD + r0 + c4 * 16;
    *(short8*)dst = va;
    *(short8*)(dst + 8) = vb;
}

// ---------------------------------------------------------------------------
// Fused QKV projection GEMM reading FP32 activations directly.
// A is staged via glds16 into an fp32 LDS tile [128 rows][32 k] (async, off
// the register critical path -- avoids round-6's T14 reg-staging trap; the
// issue/barrier schedule is IDENTICAL to the proven round-8 kernel, loads
// get a full K-iteration of latency cover). Conversion to bf16 happens on
// the LDS->register fragment path: 2x ds_read_b128 + 4x v_cvt_pk_bf16_f32
// per fragment (VALU, hidden under 16 MFMA).
// Bank-conflict fix (T2, both-sides-or-neither): fp32 rows are 128B so a
// naive column read is 16-way conflicted. Per-lane GLOBAL source chunk is
// pre-swizzled (slot ^ (row&7)), LDS dest stays linear (glds16 constraint),
// and the read XORs the slot -> 2-way (free).
// B (weights) unchanged: bf16 glds16. 2-phase single-barrier dbuf.
// XCD swizzle: XCD k owns m-blocks [4k,4k+4). V (z==2) swapped-operand
// epilogue stores directly to Vbt[bh][dk][t]. LDS 48KB -> 3 blocks/CU.
// ---------------------------------------------------------------------------
__global__ __launch_bounds__(256, 3)
void gemm_qkv(const float* __restrict__ Aqf, const float* __restrict__ Akf,
              const float* __restrict__ Avf,
              const short* __restrict__ Wqt, const short* __restrict__ Wkt,
              const short* __restrict__ Wvt,
              const float* __restrict__ bq, const float* __restrict__ bk,
              const float* __restrict__ bv,
              short* __restrict__ Qb, short* __restrict__ Kb,
              short* __restrict__ Vbt)
{
    __shared__ float Af[2][128 * 32];    // 32 KB: [buf][row][slot*4] swizzled
    __shared__ short Bs[2][128 * 32];    // 16 KB

    // bijective XCD swizzle over 768 blocks: d%8 = XCD k; j = d/8 in [0,96):
    // m_local = j&3 (fastest), n_blk = (j>>2)&7, z = j>>5; m_blk = 4k+m_local
    const int d = blockIdx.x + 8 * blockIdx.y + 256 * blockIdx.z;
    const int kx = d & 7, j = d >> 3;
    const int z = j >> 5;
    const int n0 = ((j >> 2) & 7) * 128;
    const int m0 = (4 * kx + (j & 3)) * 128;

    const float* A  = (z == 0) ? Aqf : (z == 1) ? Akf : Avf;
    const short* Bt = (z == 0) ? Wqt : (z == 1) ? Wkt : Wvt;
    const float* bias = (z == 0) ? bq : (z == 1) ? bk : bv;

    const int tid = threadIdx.x;
    const int w = tid >> 6, l = tid & 63;
    const int l15 = l & 15, quad = l >> 4;
    const int wm = w >> 1, wn = w & 1;
    const int r = tid >> 2, cseg = tid & 3;

    f32x4 acc[4][4];
#pragma unroll
    for (int i = 0; i < 4; i++)
#pragma unroll
        for (int jj = 0; jj < 4; jj++) acc[i][jj] = (f32x4){0.f, 0.f, 0.f, 0.f};

    // A-staging: call c covers rows c*32+(tid>>3), slot tid&7 (16B = 4 f32).
    // Pre-swizzled source chunk = slot ^ (row&7); row&7 == (tid>>3)&7.
    const int arow_s = tid >> 3, aslot = tid & 7;
    const int aswz = (aslot ^ (arow_s & 7)) * 4;
    const float* gA = A + (size_t)(m0 + arow_s) * DD + aswz;
    const short* gB = Bt + (size_t)(n0 + r) * DD + cseg * 8;

#define STAGE_QKV(buf, k0)                                                    \
    do {                                                                      \
        glds16(gA + (k0),                     &Af[buf][0 * 1024 + tid * 4]);  \
        glds16(gA + (size_t)32 * DD + (k0),   &Af[buf][1 * 1024 + tid * 4]);  \
        glds16(gA + (size_t)64 * DD + (k0),   &Af[buf][2 * 1024 + tid * 4]);  \
        glds16(gA + (size_t)96 * DD + (k0),   &Af[buf][3 * 1024 + tid * 4]);  \
        glds16(gB + (k0),                     &Bs[buf][w * 512]);             \
        glds16(gB + (size_t)64 * DD + (k0),   &Bs[buf][2048 + w * 512]);      \
    } while (0)
    // NOTE: glds16 dest is wave-uniform base + lane*16B; &Af[buf][c*1024+tid*4]
    // evaluates per-lane but the lane-varying part is exactly lane*16B within
    // each wave's uniform base (tid*4 floats = 16B*tid), matching rows
    // c*32 + tid>>3, slot tid&7 at byte (tid>>3)*128 + (tid&7)*16. Linear. ✓

    STAGE_QKV(0, 0);

    for (int k0 = 0; k0 < DD; k0 += 32) {
        const int cur = (k0 >> 5) & 1;
        __syncthreads();   // buf `cur` staged (vmcnt drained); buf^1 readers done
        if (k0 + 32 < DD) STAGE_QKV(cur ^ 1, k0 + 32);

        short8 bF[4];
#pragma unroll
        for (int ni = 0; ni < 4; ni++)
            bF[ni] = *(const short8*)&Bs[cur][(wn * 64 + ni * 16 + l15) * 32 + quad * 8];

        if (z != 2) {
#pragma unroll
            for (int mi = 0; mi < 4; mi++) {
                const int arow = wm * 64 + mi * 16 + l15;
                const int rx = (arow & 7);
                f32x4 u = *(const f32x4*)&Af[cur][arow * 32 + ((quad * 2) ^ rx) * 4];
                f32x4 v = *(const f32x4*)&Af[cur][arow * 32 + ((quad * 2 + 1) ^ rx) * 4];
                short8 aF = cvt8(u, v);
#pragma unroll
                for (int ni = 0; ni < 4; ni++)
                    acc[mi][ni] = __builtin_amdgcn_mfma_f32_16x16x32_bf16(aF, bF[ni], acc[mi][ni], 0, 0, 0);
            }
        } else {
            // swapped operands: acc[ni][mi] = C^T fragment (rows = n, cols = m)
#pragma unroll
            for (int mi = 0; mi < 4; mi++) {
                const int arow = wm * 64 + mi * 16 + l15;
                const int rx = (arow & 7);
                f32x4 u = *(const f32x4*)&Af[cur][arow * 32 + ((quad * 2) ^ rx) * 4];
                f32x4 v = *(const f32x4*)&Af[cur][arow * 32 + ((quad * 2 + 1) ^ rx) * 4];
                short8 aF = cvt8(u, v);
#pragma unroll
                for (int ni = 0; ni < 4; ni++)
                    acc[ni][mi] = __builtin_amdgcn_mfma_f32_16x16x32_bf16(bF[ni], aF, acc[ni][mi], 0, 0, 0);
            }
        }
    }
#undef STAGE_QKV

    if (z != 2) {
        short* dst = (z == 0) ? Qb : Kb;
        const float scale = (z == 0) ? 0.1803368801f : 1.0f;
#pragma unroll
        for (int mi = 0; mi < 4; mi++) {
#pragma unroll
            for (int reg = 0; reg < 4; reg++) {
                int m = m0 + wm * 64 + mi * 16 + quad * 4 + reg;
                int b = m >> 11, t = m & 2047;
#pragma unroll
                for (int ni = 0; ni < 4; ni++) {
                    int n = n0 + wn * 64 + ni * 16 + l15;
                    float vv = (acc[mi][ni][reg] + bias[n]) * scale;
                    int h = n >> 6, dk = n & 63;
                    dst[((size_t)(b * HH + h) * TT + t) * DKK + dk] = f2bf(vv);
                }
            }
        }
    } else {
        // acc[ni][mi]: row (quad*4+reg) = n-side, col l15 = m-side
        const int b = m0 >> 11;
        const int tl0 = (m0 & 2047) + wm * 64;
#pragma unroll
        for (int ni = 0; ni < 4; ni++) {
#pragma unroll
            for (int reg = 0; reg < 4; reg++) {
                int n = n0 + wn * 64 + ni * 16 + quad * 4 + reg;
                int h = n >> 6, dk = n & 63;
                float bb = bias[n];
                short* vrow = Vbt + ((size_t)(b * HH + h) * DKK + dk) * SSQ;
#pragma unroll
                for (int mi = 0; mi < 4; mi++) {
                    int t = tl0 + mi * 16 + l15;
                    vrow[t] = f2bf(acc[ni][mi][reg] + bb);
                }
            }
        }
    }
}

// ---------------------------------------------------------------------------
// Output projection GEMM: out[M][D] = Ab @ Wot^T + bo, fp32 out.
// 64x64 tiles, BK=64, grid 1024 = 4 blocks/CU. Unchanged from round 11.
// ---------------------------------------------------------------------------
__global__ __launch_bounds__(256, 4)
void gemm_out(const short* __restrict__ Ab, const short* __restrict__ Wot,
              const float* __restrict__ bo, float* __restrict__ out)
{
    __shared__ short As[2][2 * 64 * 32];   // [buf][panel][row][32]
    __shared__ short Bs[2][2 * 64 * 32];   // [buf][panel][row][32]

    const int d = blockIdx.x;
    const int kx = d & 7, j = d >> 3;
    const int m0 = (8 * kx + (j & 7)) * 64;
    const int n0 = (j >> 3) * 64;

    const int tid = threadIdx.x;
    const int w = tid >> 6, l = tid & 63;
    const int l15 = l & 15, quad = l >> 4;
    const int wm = w >> 1, wn = w & 1;

    f32x4 acc[2][2];
#pragma unroll
    for (int i = 0; i < 2; i++)
#pragma unroll
        for (int jj = 0; jj < 2; jj++) acc[i][jj] = (f32x4){0.f, 0.f, 0.f, 0.f};

    const int r = tid >> 2, cseg = tid & 3;
    const short* gA = Ab + (size_t)(m0 + r) * DD + cseg * 8;
    const short* gB = Wot + (size_t)(n0 + r) * DD + cseg * 8;

#define STAGE_OUT(buf, k0)                                        \
    do {                                                          \
        glds16(gA + (k0),      &As[buf][w * 512]);                \
        glds16(gA + (k0) + 32, &As[buf][2048 + w * 512]);         \
        glds16(gB + (k0),      &Bs[buf][w * 512]);                \
        glds16(gB + (k0) + 32, &Bs[buf][2048 + w * 512]);         \
    } while (0)

    STAGE_OUT(0, 0);

    for (int k0 = 0; k0 < DD; k0 += 64) {
        const int cur = (k0 >> 6) & 1;
        __syncthreads();
        if (k0 + 64 < DD) STAGE_OUT(cur ^ 1, k0 + 64);

#pragma unroll
        for (int kk = 0; kk < 2; kk++) {
            short8 bF[2];
#pragma unroll
            for (int ni = 0; ni < 2; ni++)
                bF[ni] = *(const short8*)&Bs[cur][kk * 2048 + (wn * 32 + ni * 16 + l15) * 32 + quad * 8];
#pragma unroll
            for (int mi = 0; mi < 2; mi++) {
                short8 aF = *(const short8*)&As[cur][kk * 2048 + (wm * 32 + mi * 16 + l15) * 32 + quad * 8];
#pragma unroll
                for (int ni = 0; ni < 2; ni++)
                    acc[mi][ni] = __builtin_amdgcn_mfma_f32_16x16x32_bf16(aF, bF[ni], acc[mi][ni], 0, 0, 0);
            }
        }
    }
#undef STAGE_OUT

#pragma unroll
    for (int mi = 0; mi < 2; mi++) {
#pragma unroll
        for (int reg = 0; reg < 4; reg++) {
            int m = m0 + wm * 32 + mi * 16 + quad * 4 + reg;
#pragma unroll
            for (int ni = 0; ni < 2; ni++) {
                int n = n0 + wn * 32 + ni * 16 + l15;
                out[(size_t)m * DD + n] = acc[mi][ni][reg] + bo[n];
            }
        }
    }
}

// ---------------------------------------------------------------------------
// bf16 MFMA flash attention, FULL-S, BT=128, 4 waves, grid (16,32) = 512.
// lacc MFMA row-sum -> zero-shuffle epilogue. Proven 48.9us — FROZEN.
// ---------------------------------------------------------------------------
__global__ __launch_bounds__(256, 3)
void attn_mfma(const short* __restrict__ Qb, const short* __restrict__ Kb,
               const short* __restrict__ Vbt, short* __restrict__ Ab)
{
    // [dbuf][{K|V}] each 64x72 shorts: K at dbo, V at dbo+4608
    __shared__ short KV[2 * 2 * 64 * 72];   // 36864 B

    const int tid = threadIdx.x;
    const int w = tid >> 6, l = tid & 63;
    const int l15 = l & 15, quad = l >> 4;

    // bijective XCD swizzle: fid -> (tile, bh); XCD k gets bh in [4k,4k+4)
    const int fid = blockIdx.y * 16 + blockIdx.x;
    const int swz = (fid & 7) * 64 + (fid >> 3);
    const int t0 = (swz & 15) * 128;
    const int bh = swz >> 4;
    const size_t hb = (size_t)bh * SSQ * DKK;
    const int r = tid >> 2, c4 = tid & 3;

    // ---- Q fragments direct from global (B-operand layout, reused 32 tiles)
    short8 qf[2][2];
#pragma unroll
    for (int mf = 0; mf < 2; mf++)
#pragma unroll
        for (int kk = 0; kk < 2; kk++)
            qf[mf][kk] = *(const short8*)(Qb + hb +
                (size_t)(t0 + 32 * w + 16 * mf + l15) * DKK + kk * 32 + quad * 8);

    // ---- prefetch K/V tile 0 ----
    const short* gkb = Kb + hb + (size_t)r * DKK + c4 * 16;
    const short* gvb = Vbt + hb + (size_t)r * SSQ + c4 * 16;
    short8 kr0 = *(const short8*)(gkb + 0);
    short8 kr1 = *(const short8*)(gkb + 8);
    short8 vr0 = *(const short8*)(gvb + 0);
    short8 vr1 = *(const short8*)(gvb + 8);

    f32x4 o[2][4];
#pragma unroll
    for (int mf = 0; mf < 2; mf++)
#pragma unroll
        for (int j = 0; j < 4; j++) o[mf][j] = (f32x4){0.f, 0.f, 0.f, 0.f};
    f32x4 lacc[2] = {(f32x4){0.f, 0.f, 0.f, 0.f}, (f32x4){0.f, 0.f, 0.f, 0.f}};
    const short8 ones = {(short)0x3F80, (short)0x3F80, (short)0x3F80, (short)0x3F80,
                         (short)0x3F80, (short)0x3F80, (short)0x3F80, (short)0x3F80};

    short* skb = KV + r * 72 + c4 * 16;   // staging write base

    for (int s0 = 0; s0 < SSQ; s0 += 64) {
        const int dbo = (s0 & 64) ? 9216 : 0;
        // write current K/V regs into buffer `dbo`
        *(short8*)(skb + dbo)          = kr0;
        *(short8*)(skb + dbo + 8)      = kr1;
        *(short8*)(skb + dbo + 4608)   = vr0;
        *(short8*)(skb + dbo + 4616)   = vr1;
        // issue next-tile global loads (covered by this tile's compute)
        if (s0 + 64 < SSQ) {
            const short* gk = gkb + (size_t)(s0 + 64) * DKK;
            const short* gv = gvb + (s0 + 64);
            kr0 = *(const short8*)(gk + 0);
            kr1 = *(const short8*)(gk + 8);
            vr0 = *(const short8*)(gv + 0);
            vr1 = *(const short8*)(gv + 8);
        }
        __syncthreads();          // tile `dbo` visible; prev-buffer readers done
        const short* kb_ = KV + dbo;
        const short* vb_ = kb_ + 4608;

        // ---- S^T = K Q^T : lane holds q-row l15, s = 16np+4quad+reg ----
        f32x4 sc[4][2];
#pragma unroll
        for (int np = 0; np < 4; np++)
#pragma unroll
            for (int mf = 0; mf < 2; mf++) sc[np][mf] = (f32x4){0.f, 0.f, 0.f, 0.f};
        __builtin_amdgcn_s_setprio(1);
#pragma unroll
        for (int kk = 0; kk < 2; kk++) {
#pragma unroll
            for (int np = 0; np < 4; np++) {
                short8 aK = *(const short8*)&kb_[(16 * np + l15) * 72 + kk * 32 + quad * 8];
                sc[np][0] = __builtin_amdgcn_mfma_f32_16x16x32_bf16(aK, qf[0][kk], sc[np][0], 0, 0, 0);
                sc[np][1] = __builtin_amdgcn_mfma_f32_16x16x32_bf16(aK, qf[1][kk], sc[np][1], 0, 0, 0);
            }
        }
        __builtin_amdgcn_s_setprio(0);

        // ---- P = exp2(S); inline pack + permlane into PV A-frags ----
        short8 pa[2][2];
#pragma unroll
        for (int mf = 0; mf < 2; mf++) {
#pragma unroll
            for (int kk = 0; kk < 2; kk++) {
                u32x4 wd;
#pragma unroll
                for (int b = 0; b < 2; b++) {
                    float p00 = __builtin_amdgcn_exp2f(sc[2 * kk][mf][2 * b]);
                    float p01 = __builtin_amdgcn_exp2f(sc[2 * kk][mf][2 * b + 1]);
                    float p10 = __builtin_amdgcn_exp2f(sc[2 * kk + 1][mf][2 * b]);
                    float p11 = __builtin_amdgcn_exp2f(sc[2 * kk + 1][mf][2 * b + 1]);
                    unsigned Xw = pk2(p00, p01);
                    unsigned Yw = pk2(p10, p11);
                    uint2v s1 = __builtin_amdgcn_permlane32_swap(Xw, Yw, false, false);
                    uint2v s2 = __builtin_amdgcn_permlane16_swap(s1[0], s1[1], false, false);
                    wd[b]     = s2[0];
                    wd[2 + b] = s2[1];
                }
                pa[mf][kk] = __builtin_bit_cast(short8, wd);
            }
        }

        // ---- O += P V ; lacc += P * ones (row-sum l on matrix pipe) ----
        __builtin_amdgcn_s_setprio(1);
#pragma unroll
        for (int kk = 0; kk < 2; kk++) {
            lacc[0] = __builtin_amdgcn_mfma_f32_16x16x32_bf16(pa[0][kk], ones, lacc[0], 0, 0, 0);
            lacc[1] = __builtin_amdgcn_mfma_f32_16x16x32_bf16(pa[1][kk], ones, lacc[1], 0, 0, 0);
#pragma unroll
            for (int np = 0; np < 4; np++) {
                short8 bV = *(const short8*)&vb_[(16 * np + l15) * 72 + kk * 32 + quad * 8];
                o[0][np] = __builtin_amdgcn_mfma_f32_16x16x32_bf16(pa[0][kk], bV, o[0][np], 0, 0, 0);
                o[1][np] = __builtin_amdgcn_mfma_f32_16x16x32_bf16(pa[1][kk], bV, o[1][np], 0, 0, 0);
            }
        }
        __builtin_amdgcn_s_setprio(0);
    }

    // ---- epilogue: zero-shuffle normalize (lacc holds own-row l), write ----
    const int b = bh >> 4, h = bh & 15;
#pragma unroll
    for (int mf = 0; mf < 2; mf++) {
#pragma unroll
        for (int reg = 0; reg < 4; reg++) {
            float inv = 1.f / lacc[mf][reg];
            int t = t0 + 32 * w + 16 * mf + quad * 4 + reg;
#pragma unroll
            for (int np = 0; np < 4; np++) {
                Ab[((size_t)(b * TT + t) * HH + h) * DKK + 16 * np + l15] =
                    f2bf(o[mf][np][reg] * inv);
            }
        }
    }
}

// ---------------------------------------------------------------------------
extern "C" void kernel_launch(void* const* d_in, const int* in_sizes, int n_in,
                              void* d_out, int out_size, void* d_ws, size_t ws_size,
                              hipStream_t stream)
{
    const float* query = (const float*)d_in[0];
    const float* value = (const float*)d_in[1];
    const float* key   = (const float*)d_in[2];
    const float* Wq    = (const float*)d_in[3];
    const float* bq    = (const float*)d_in[4];
    const float* Wk    = (const float*)d_in[5];
    const float* bk    = (const float*)d_in[6];
    const float* Wv    = (const float*)d_in[7];
    const float* bv    = (const float*)d_in[8];
    const float* Wo    = (const float*)d_in[9];
    const float* bo    = (const float*)d_in[10];
    float* out = (float*)d_out;

    const size_t actE = (size_t)MM * DD;    // 4.19M elems
    const size_t wE   = (size_t)DD * NN;    // 1.05M elems
    short* p = (short*)d_ws;
    short* Wqt  = p; p += wE;
    short* Wkt  = p; p += wE;
    short* Wvt  = p; p += wE;
    short* Wot  = p; p += wE;
    short* Qb   = p; p += actE;
    short* Kb   = p; p += actE;
    short* Vbt  = p; p += actE;
    short* Ab   = p; p += actE;

    dim3 blk(256);

    // 1. weight transpose/convert only (activation pass deleted)
    wprep<<<dim3(1024), blk, 0, stream>>>(Wq, Wk, Wv, Wo, Wqt, Wkt, Wvt, Wot);

    // 2. fused QKV projections from fp32 activations (glds16 fp32-LDS +
    //    cvt-on-read, swizzled); V written transposed
    gemm_qkv<<<dim3(NN / 128, MM / 128, 3), blk, 0, stream>>>(
        query, key, value, Wqt, Wkt, Wvt, bq, bk, bv, Qb, Kb, Vbt);

    // 3. flash attention (full-S, zero-shuffle epilogue) -> bf16 Ab
    attn_mfma<<<dim3(TT / 128, BB * HH), blk, 0, stream>>>(Qb, Kb, Vbt, Ab);

    // 4. output projection (64x64 tiles, 4 blocks/CU) -> fp32 out
    gemm_out<<<dim3(1024), blk, 0, stream>>>(Ab, Wot, bo, out);
}